// Round 11
// baseline (21.784 us; speedup 1.0000x reference)
//
#include <hip/hip_runtime.h>
#include <float.h>

#define GDIM 12
#define NC   144          // GDIM*GDIM
#define FINF 1.0e9f

// DPP lane permutes within 16-lane rows.
// 0x121/0x12F: row_ror 1/15 (idle lanes 12..15 = FINF are the boundary guard;
// both directions min'd, so convention is irrelevant).
// 0xB1/0x4E: quad_perm xor1/xor2; 0x141: row_half_mirror; 0x140: row_mirror.
template<int CTRL>
__device__ inline float rot(float x) {
    return __int_as_float(__builtin_amdgcn_update_dpp(
        __float_as_int(x), __float_as_int(x), CTRL, 0xf, 0xf, false));
}

// Sequential GS row update (boundary rows specialized). Exact reference
// expression: D[i] = min(D[i], C[i] + min(8 neighbors)).
#define ROWU(i, C, D) {                                                    \
    float V = ((i) == 0)        ? D[1] :                                   \
              ((i) == GDIM - 1) ? D[GDIM - 2] :                            \
              fminf(D[(i) > 0 ? (i)-1 : 0], D[(i) < GDIM-1 ? (i)+1 : GDIM-1]); \
    float cm3 = fminf(V, D[(i)]);                                          \
    float nbr = fminf(fminf(rot<0x121>(cm3), rot<0x12F>(cm3)), V);         \
    D[(i)] = fminf(D[(i)], C[(i)] + nbr); }

// Seam-split sweeps: two independent GS chains (rows 0..5 and 6..11),
// textually interleaved for 2-way ILP. Seam rows read the cross-seam
// value from the PREVIOUS sweep (legal chaotic monotone relaxation; each
// sweep still pointwise-dominates one Jacobi sweep, preserving the
// 40-cycle >= 144-Jacobi-sweep guarantee).
#define SWEEP_DN2(C, D) {                                                  \
    ROWU(0,C,D) ROWU(6,C,D) ROWU(1,C,D) ROWU(7,C,D)                        \
    ROWU(2,C,D) ROWU(8,C,D) ROWU(3,C,D) ROWU(9,C,D)                        \
    ROWU(4,C,D) ROWU(10,C,D) ROWU(5,C,D) ROWU(11,C,D) }
#define SWEEP_UP2(C, D) {                                                  \
    ROWU(11,C,D) ROWU(5,C,D) ROWU(10,C,D) ROWU(4,C,D)                      \
    ROWU(9,C,D) ROWU(3,C,D) ROWU(8,C,D) ROWU(2,C,D)                        \
    ROWU(7,C,D) ROWU(1,C,D) ROWU(6,C,D) ROWU(0,C,D) }

__global__ __launch_bounds__(512)
void path_kernel(const int* __restrict__ w,
                 const float* __restrict__ costs,
                 int* __restrict__ out) {
    const int t  = threadIdx.x;     // 0..511
    const int wv = t >> 6;          // wave 0..7 (fully independent)
    const int l  = t & 63;          // lane 0..63
    const int g  = l >> 4;          // problem group 0..3 within the wave
    const int j  = l & 15;          // column (0..11 active, 12..15 idle=INF)
    const int pw = blockIdx.x * 32 + wv * 4;   // this wave's first problem

    __shared__ int4  s_w4[8][NC];   // per-wave weights (4 problems each)
    __shared__ float dl[8][4][200]; // per-wave per-group 14x14 padded dist

    // prefetch this wave's weights (hide HBM latency under LDS init)
    const int4* wvp = (const int4*)(w + (size_t)pw * NC);
    int4 wA = wvp[l];
    int4 wB = wvp[64 + l];
    int4 wC = (l < 16) ? wvp[128 + l] : make_int4(0, 0, 0, 0);

    // early zero-fill of this wave's output slice (overlaps with relax;
    // backtrack later overwrites path cells with 1 after a vmcnt fence)
    {
        int4* ov = (int4*)(out + (size_t)pw * NC);
        const int4 z = make_int4(0, 0, 0, 0);
        ov[l] = z;
        ov[64 + l] = z;
        if (l < 16) ov[128 + l] = z;
    }

    // uniform scalar loads of the 5-entry cost table (broadcast)
    const float cv0 = costs[0], cv1 = costs[1], cv2 = costs[2],
                cv3 = costs[3], cv4 = costs[4];

    // per-wave LDS init (no cross-wave sharing -> no barriers anywhere)
    float* dlw = &dl[wv][0][0];
    #pragma unroll
    for (int q = 0; q < 13; ++q) { int idx = q * 64 + l; if (idx < 800) dlw[idx] = FINF; }

    s_w4[wv][l] = wA;
    s_w4[wv][64 + l] = wB;
    if (l < 16) s_w4[wv][128 + l] = wC;

    const bool act = (j < GDIM);
    const int* sw = (const int*)s_w4[wv];
    float* A = &dl[wv][g][0];

    // c  = normal layout: lane j owns column j, reg i = row i  -> cell (i,j)
    // ct = transposed   : lane j owns row    j, reg i = col i  -> cell (j,i)
    float c[GDIM], ct[GDIM], d[GDIM];
    #pragma unroll
    for (int i = 0; i < GDIM; ++i) {
        int wiN = sw[g * NC + i * GDIM + (act ? j : 0)];
        int wiT = sw[act ? (g * NC + j * GDIM + i) : 0];
        float cN = cv4, cT = cv4;
        cN = (wiN == 0) ? cv0 : cN;  cT = (wiT == 0) ? cv0 : cT;
        cN = (wiN == 1) ? cv1 : cN;  cT = (wiT == 1) ? cv1 : cT;
        cN = (wiN == 2) ? cv2 : cN;  cT = (wiT == 2) ? cv2 : cT;
        cN = (wiN == 3) ? cv3 : cN;  cT = (wiT == 3) ? cv3 : cT;
        c[i]  = act ? cN : FINF;
        ct[i] = act ? cT : FINF;
        d[i]  = FINF;
    }
    if (j == 0) d[0] = c[0];        // source cell (0,0)

    // Cycle: seam-split {down,up} normal, LDS transpose, seam-split
    // {right,left} transposed, transpose back; convergence by snapshot
    // compare from cycle 2 on (no problem converges earlier). Monotone
    // relaxation -> reference's exact f32 fixed point; cap 40 cycles =
    // 160 Jacobi-dominating sweeps >= reference's 144.
    #pragma unroll 1
    for (int cyc = 0; cyc < 40; ++cyc) {
        const bool chk = (cyc >= 2);
        float dp[GDIM];
        if (chk) {
            #pragma unroll
            for (int i = 0; i < GDIM; ++i) dp[i] = d[i];
        }

        SWEEP_DN2(c, d)
        SWEEP_UP2(c, d)

        if (act) {
            #pragma unroll
            for (int i = 0; i < GDIM; ++i) A[(i + 1) * 14 + (j + 1)] = d[i];
            #pragma unroll
            for (int i = 0; i < GDIM; ++i) d[i] = A[(j + 1) * 14 + (i + 1)];
        }

        SWEEP_DN2(ct, d)
        SWEEP_UP2(ct, d)

        if (act) {
            #pragma unroll
            for (int i = 0; i < GDIM; ++i) A[(j + 1) * 14 + (i + 1)] = d[i];
            #pragma unroll
            for (int i = 0; i < GDIM; ++i) d[i] = A[(i + 1) * 14 + (j + 1)];
        }

        if (chk) {
            bool ch = false;
            #pragma unroll
            for (int i = 0; i < GDIM; ++i) ch = ch | (d[i] < dp[i]);
            if (__ballot(ch) == 0ull) break;
        }
    }

    // fence: all zero-stores complete before path stores (same-wave order)
    asm volatile("s_waitcnt vmcnt(0)" ::: "memory");

    // ---- parallel backtrack, writing 1s directly to global ----
    // Lanes j<8 each load one neighbor (padded DIRS offsets -15,-14,-13,
    // -1,1,13,14,15 == j-15 | -1 | 1 | j+8); 4-step DPP min-butterfly
    // (min idempotent -> quad xor1, xor2, half-mirror, mirror covers 16);
    // ballot lowest-set-bit = lowest dir index among ties = reference's
    // first-wins argmin. a = padded idx, n = flat idx (n-step = a-step+2*di).
    {
        int* outg = out + (size_t)(pw + g) * NC;
        const int offj = (j < 3) ? (j - 15) : (j == 3) ? -1 : (j == 4) ? 1 : (j + 8);
        int a = 12 * 14 + 12;       // padded (11,11)
        int n = NC - 1;             // flat 143
        if (j == 0) outg[n] = 1;
        const int target = 1 * 14 + 1;
        for (int s = 0; s < NC; ++s) {
            if (__ballot(a != target) == 0ull) break;
            float v = (j < 8) ? A[a + offj] : FINF;   // in-bounds even when done
            float m = v;
            m = fminf(m, rot<0xB1>(m));    // xor1 within quads
            m = fminf(m, rot<0x4E>(m));    // xor2 -> min of each quad
            m = fminf(m, rot<0x141>(m));   // half-mirror -> min of 8
            m = fminf(m, rot<0x140>(m));   // mirror -> min of 16
            unsigned long long bal = __ballot((j < 8) & (v == m));
            int mask8 = (int)(bal >> (g * 16)) & 0xFF;
            int bidx = __ffs(mask8) - 1;   // first-wins tie (lowest dir idx)
            if (a != target) {
                int off = (bidx < 3) ? (bidx - 15) : (bidx == 3) ? -1
                        : (bidx == 4) ? 1 : (bidx + 8);
                int adj = (bidx < 3) ? 2 : (bidx > 4) ? -2 : 0;
                a += off;
                n += off + adj;
                if (j == 0) outg[n] = 1;
            }
        }
    }
}

extern "C" void kernel_launch(void* const* d_in, const int* in_sizes, int n_in,
                              void* d_out, int out_size, void* d_ws, size_t ws_size,
                              hipStream_t stream) {
    const int*   w     = (const int*)d_in[0];
    const float* costs = (const float*)d_in[1];
    int*         out   = (int*)d_out;
    const int K = in_sizes[0] / NC;          // 8192 problems
    path_kernel<<<dim3(K / 32), dim3(512), 0, stream>>>(w, costs, out);
}

// Round 12
// 20.844 us; speedup vs baseline: 1.0451x; 1.0451x over previous
//
#include <hip/hip_runtime.h>
#include <float.h>

#define GDIM 12
#define NC   144          // GDIM*GDIM
#define FINF 1.0e9f

// DPP lane permutes within 16-lane rows.
// 0x121/0x12F: row_ror 1/15 (idle lanes 12..15 = FINF are the boundary guard;
// both directions min'd, so convention is irrelevant).
// 0xB1/0x4E: quad_perm xor1/xor2; 0x141: row_half_mirror; 0x140: row_mirror.
template<int CTRL>
__device__ inline float rot(float x) {
    return __int_as_float(__builtin_amdgcn_update_dpp(
        __float_as_int(x), __float_as_int(x), CTRL, 0xf, 0xf, false));
}

// Sequential GS row update (boundary rows specialized). Exact reference
// expression: D[i] = min(D[i], C[i] + min(8 neighbors)).
#define ROWU(i, C, D) {                                                    \
    float V = ((i) == 0)        ? D[1] :                                   \
              ((i) == GDIM - 1) ? D[GDIM - 2] :                            \
              fminf(D[(i) > 0 ? (i)-1 : 0], D[(i) < GDIM-1 ? (i)+1 : GDIM-1]); \
    float cm3 = fminf(V, D[(i)]);                                          \
    float nbr = fminf(fminf(rot<0x121>(cm3), rot<0x12F>(cm3)), V);         \
    D[(i)] = fminf(D[(i)], C[(i)] + nbr); }

#define SWEEP_DN(C, D) { _Pragma("unroll")                                 \
    for (int i = 0; i < GDIM; ++i) ROWU(i, C, D) }
// Up-sweep with fused transpose writes: after ROWU(i) the row is final for
// this sweep pair, so its LDS write issues immediately (drains during the
// rest of the sweep instead of after it). BASE/STEP give a per-lane safe
// address (idle lanes -> dummy slot 196, which holds FINF and is never read).
#define SWEEP_UP_W(C, D, AP, BASE, STEP) { _Pragma("unroll")               \
    for (int q = 0; q < GDIM; ++q) { const int i = GDIM - 1 - q;           \
        ROWU(i, C, D)                                                      \
        (AP)[(BASE) + i * (STEP)] = D[i]; } }

__global__ __launch_bounds__(512)
void path_kernel(const int* __restrict__ w,
                 const float* __restrict__ costs,
                 int* __restrict__ out) {
    const int t  = threadIdx.x;     // 0..511
    const int wv = t >> 6;          // wave 0..7 (fully independent)
    const int l  = t & 63;          // lane 0..63
    const int g  = l >> 4;          // problem group 0..3 within the wave
    const int j  = l & 15;          // column (0..11 active, 12..15 idle=INF)
    const int pw = blockIdx.x * 32 + wv * 4;   // this wave's first problem

    __shared__ int4  s_w4[8][NC];   // per-wave weights (4 problems each)
    __shared__ float dl[8][4][200]; // per-wave per-group 14x14 padded dist
    __shared__ int   ml[8][4 * NC]; // per-wave masks
    // total: 18.4 + 25.6 + 18.4 = 62.5 KB (< 64 KB/WG)

    // prefetch this wave's weights first (hide HBM latency under LDS init)
    const int4* wvp = (const int4*)(w + (size_t)pw * NC);
    int4 wA = wvp[l];
    int4 wB = wvp[64 + l];
    int4 wC = (l < 16) ? wvp[128 + l] : make_int4(0, 0, 0, 0);

    // uniform scalar loads of the 5-entry cost table (broadcast)
    const float cv0 = costs[0], cv1 = costs[1], cv2 = costs[2],
                cv3 = costs[3], cv4 = costs[4];

    // per-wave LDS init (no cross-wave sharing -> no barriers anywhere)
    int* mlw = ml[wv];
    #pragma unroll
    for (int q = 0; q < 9; ++q) mlw[q * 64 + l] = 0;
    float* dlw = &dl[wv][0][0];
    #pragma unroll
    for (int q = 0; q < 13; ++q) { int idx = q * 64 + l; if (idx < 800) dlw[idx] = FINF; }

    s_w4[wv][l] = wA;
    s_w4[wv][64 + l] = wB;
    if (l < 16) s_w4[wv][128 + l] = wC;

    const bool act = (j < GDIM);
    const int* sw = (const int*)s_w4[wv];
    float* A = &dl[wv][g][0];

    // fused-transpose write addressing:
    //   normal->transposed write: A[(i+1)*14 + (j+1)] = base (15+j), step 14
    //   transposed->normal write: A[(j+1)*14 + (i+1)] = base (j*14+15), step 1
    // idle lanes: base 196 (slack slot, FINF, never read), step 0.
    const int wrN_base = act ? (15 + j)      : 196;
    const int wrN_step = act ? 14            : 0;
    const int wrT_base = act ? (j * 14 + 15) : 196;
    const int wrT_step = act ? 1             : 0;

    // c  = normal layout: lane j owns column j, reg i = row i  -> cell (i,j)
    // ct = transposed   : lane j owns row    j, reg i = col i  -> cell (j,i)
    float c[GDIM], ct[GDIM], d[GDIM];
    #pragma unroll
    for (int i = 0; i < GDIM; ++i) {
        int wiN = sw[g * NC + i * GDIM + (act ? j : 0)];
        int wiT = sw[act ? (g * NC + j * GDIM + i) : 0];
        float cN = cv4, cT = cv4;
        cN = (wiN == 0) ? cv0 : cN;  cT = (wiT == 0) ? cv0 : cT;
        cN = (wiN == 1) ? cv1 : cN;  cT = (wiT == 1) ? cv1 : cT;
        cN = (wiN == 2) ? cv2 : cN;  cT = (wiT == 2) ? cv2 : cT;
        cN = (wiN == 3) ? cv3 : cN;  cT = (wiT == 3) ? cv3 : cT;
        c[i]  = act ? cN : FINF;
        ct[i] = act ? cT : FINF;
        d[i]  = FINF;
    }
    if (j == 0) d[0] = c[0];        // source cell (0,0)

    // Cycle: {down,up} normal (vertical-monotone segments instant; up-sweep
    // streams the transpose writes), transposed read, {right,left}
    // transposed (horizontal-monotone instant; up-sweep streams the
    // back-transpose writes), normal read; convergence by snapshot compare.
    // Cap 40 cycles = 160 GS sweeps >= reference's 144-sweep Jacobi
    // guarantee (GS dominates Jacobi pointwise). Monotone relaxation ->
    // reference's exact f32 fixed point.
    #pragma unroll 1
    for (int cyc = 0; cyc < 40; ++cyc) {
        float dp[GDIM];
        #pragma unroll
        for (int i = 0; i < GDIM; ++i) dp[i] = d[i];

        SWEEP_DN(c, d)
        SWEEP_UP_W(c, d, A, wrN_base, wrN_step)

        if (act) {
            #pragma unroll
            for (int i = 0; i < GDIM; ++i) d[i] = A[(j + 1) * 14 + (i + 1)];
        }

        SWEEP_DN(ct, d)
        SWEEP_UP_W(ct, d, A, wrT_base, wrT_step)

        if (act) {
            #pragma unroll
            for (int i = 0; i < GDIM; ++i) d[i] = A[(i + 1) * 14 + (j + 1)];
        }

        bool ch = false;
        #pragma unroll
        for (int i = 0; i < GDIM; ++i) ch = ch | (d[i] < dp[i]);
        if (__ballot(ch) == 0ull) break;
    }

    // ---- parallel backtrack: 16 lanes per group cooperate ----
    // A holds dist in normal layout (written by the last back-transpose's
    // fused writes). Lanes j<8 each load one neighbor (padded DIRS offsets
    // -15,-14,-13,-1,1,13,14,15 == j-15 | -1 | 1 | j+8); 4-step DPP
    // min-butterfly (min idempotent -> quad xor1, xor2, half-mirror, mirror
    // covers 16); ballot lowest-set-bit = lowest dir index among ties =
    // reference's first-wins argmin. a = padded idx, n = flat idx.
    {
        int* mlg = mlw + g * NC;
        const int offj = (j < 3) ? (j - 15) : (j == 3) ? -1 : (j == 4) ? 1 : (j + 8);
        int a = 12 * 14 + 12;       // padded (11,11)
        int n = NC - 1;             // flat 143
        if (j == 0) mlg[n] = 1;
        const int target = 1 * 14 + 1;
        for (int s = 0; s < NC; ++s) {
            if (__ballot(a != target) == 0ull) break;
            float v = (j < 8) ? A[a + offj] : FINF;   // in-bounds even when done
            float m = v;
            m = fminf(m, rot<0xB1>(m));    // xor1 within quads
            m = fminf(m, rot<0x4E>(m));    // xor2 -> min of each quad
            m = fminf(m, rot<0x141>(m));   // half-mirror -> min of 8
            m = fminf(m, rot<0x140>(m));   // mirror -> min of 16
            unsigned long long bal = __ballot((j < 8) & (v == m));
            int mask8 = (int)(bal >> (g * 16)) & 0xFF;
            int bidx = __ffs(mask8) - 1;   // first-wins tie (lowest dir idx)
            if (a != target) {
                int off = (bidx < 3) ? (bidx - 15) : (bidx == 3) ? -1
                        : (bidx == 4) ? 1 : (bidx + 8);
                int adj = (bidx < 3) ? 2 : (bidx > 4) ? -2 : 0;
                a += off;
                n += off + adj;
                if (j == 0) mlg[n] = 1;
            }
        }
    }

    // ---- int4 coalesced store (writes every output element) ----
    int4* ov = (int4*)(out + (size_t)pw * NC);
    const int4* ml4w = (const int4*)mlw;
    ov[l] = ml4w[l];
    ov[64 + l] = ml4w[64 + l];
    if (l < 16) ov[128 + l] = ml4w[128 + l];
}

extern "C" void kernel_launch(void* const* d_in, const int* in_sizes, int n_in,
                              void* d_out, int out_size, void* d_ws, size_t ws_size,
                              hipStream_t stream) {
    const int*   w     = (const int*)d_in[0];
    const float* costs = (const float*)d_in[1];
    int*         out   = (int*)d_out;
    const int K = in_sizes[0] / NC;          // 8192 problems
    path_kernel<<<dim3(K / 32), dim3(512), 0, stream>>>(w, costs, out);
}